// Round 10
// baseline (157.565 us; speedup 1.0000x reference)
//
#include <hip/hip_runtime.h>

#define A_N   4096
#define EMBED 128
#define MAXO  16
#define DEG   8
#define OBSD  8
#define ORIG  18
#define KCAND 128            // DEG*MAXO candidates per agent
#define G     4              // agents per block
#define NBLK  (A_N / G)      // 1024 blocks
#define NTHR  512            // 8 waves/block -> 4 blocks/CU = 32 waves/CU
#define EL    (MAXO * ORIG)  // 288
#define NQ    (MAXO + 1)     // 17
#define THRES2 (0.02f * 0.02f)

// concurrent-phase thread ranges (WAVE-ALIGNED: no wave runs two loops)
#define EP_END    288        // e-pair units: threads 0..287 (waves 0..4L)
#define LG_BEG    320        // logit units:  threads 320..455 (waves 5..7L)
#define LG_END    456

// ---------------------------------------------------------------------------
// Prep: fuse the pure-linear chains through W2:
//   A-side: fWxA = enc_W2@mdec_Wx, fbxA = enc_b2@mdec_Wx + mdec_bx,
//           fWsA = enc_W2@mdec_Ws, fbsA = enc_b2@mdec_Ws + mdec_bs
//   B-side: same with menc_W2/menc_b2 and dec_*.
// 258 blocks x 320 thr: block (side, r): r<128 -> row r of W2; r==128 -> bias.
// ---------------------------------------------------------------------------
__global__ __launch_bounds__(320) void prep_kernel(
    const float* __restrict__ enc_W2, const float* __restrict__ enc_b2,
    const float* __restrict__ mdec_Wx, const float* __restrict__ mdec_Ws,
    const float* __restrict__ mdec_bx, const float* __restrict__ mdec_bs,
    const float* __restrict__ menc_W2, const float* __restrict__ menc_b2,
    const float* __restrict__ dec_Wx, const float* __restrict__ dec_Ws,
    const float* __restrict__ dec_bx, const float* __restrict__ dec_bs,
    float* __restrict__ fWxA, float* __restrict__ fbxA,
    float* __restrict__ fWsA, float* __restrict__ fbsA,
    float* __restrict__ fWxB, float* __restrict__ fbxB,
    float* __restrict__ fWsB, float* __restrict__ fbsB)
{
    const int b = blockIdx.x, tid = threadIdx.x;
    const int side = b / 129, r = b % 129;
    const float* W2 = side ? menc_W2 : enc_W2;
    const float* b2 = side ? menc_b2 : enc_b2;
    const float* Wx = side ? dec_Wx : mdec_Wx;
    const float* Ws = side ? dec_Ws : mdec_Ws;
    const float* bx = side ? dec_bx : mdec_bx;
    const float* bs = side ? dec_bs : mdec_bs;
    float* oWx = side ? fWxB : fWxA;
    float* obx = side ? fbxB : fbxA;
    float* oWs = side ? fWsB : fWsA;
    float* obs_ = side ? fbsB : fbsA;

    __shared__ float rv[EMBED];
    if (tid < EMBED) rv[tid] = (r < EMBED) ? W2[r * EMBED + tid] : b2[tid];
    __syncthreads();

    if (tid < EL) {
        float acc = 0.f;
        for (int t = 0; t < EMBED; ++t) acc += rv[t] * Wx[t * EL + tid];
        if (r < EMBED) oWx[r * EL + tid] = acc;
        else           obx[tid] = acc + bx[tid];
    } else if (tid < EL + NQ) {
        const int q = tid - EL;
        float acc = 0.f;
        for (int t = 0; t < EMBED; ++t) acc += rv[t] * Ws[t * NQ + q];
        if (r < EMBED) oWs[r * NQ + q] = acc;
        else           obs_[q] = acc + bs[q];
    }
}

// ---------------------------------------------------------------------------
// Kernel A: 4 source agents, 512 threads. Phases: msg gather -> segsum S ->
// {elems e-pairs from S (waves 0-4) || npred logits from S (waves 5-7)} ->
// combine (elems + pxy_base + logits) -> argmax.  (W2 GEMV fused away.)
// ---------------------------------------------------------------------------
__global__ __launch_bounds__(NTHR, 8) void enc512_kernel(
    const float* __restrict__ obj_x, const float* __restrict__ obj_pos,
    const float* __restrict__ agent_pos,
    const float* __restrict__ enc_W1, const float* __restrict__ enc_b1,
    const float* __restrict__ fWxA, const float* __restrict__ fbxA,
    const float* __restrict__ fWsA, const float* __restrict__ fbsA,
    const int* __restrict__ obs_edge,
    float* __restrict__ elems_base, int* __restrict__ npred_out,
    float2* __restrict__ pxy_base)
{
    const int blk = blockIdx.x, tid = threadIdx.x;
    const int i0  = blk * G;
    const int col = tid & 127, q = tid >> 7;

    __shared__ int    on[G][OBSD];
    __shared__ float  msg[G * OBSD][20];
    __shared__ float4 SG[EMBED];          // segsum, [c] -> 4 agents
    __shared__ float  Lp[2][G * NQ];      // logit split-K2 partials
    __shared__ float  lgts[G][NQ];
    __shared__ float4 Pp[2][EL];          // elems split-K2 partials

    if (tid < G * OBSD) {
        const int g = tid >> 3, d = tid & 7;
        on[g][d] = obs_edge[A_N * OBSD + (i0 + g) * OBSD + d];
    }
    __syncthreads();
    for (int idx = tid; idx < G * OBSD * ORIG; idx += NTHR) {
        const int r = idx / ORIG, c = idx % ORIG;
        const int g = r >> 3, d = r & 7;
        const int o = on[g][d];
        float v;
        if (c < 16) v = obj_x[o * 16 + c];
        else        v = obj_pos[o * 2 + (c - 16)] - agent_pos[(i0 + g) * 2 + (c - 16)];
        msg[r][c] = v;
    }
    __syncthreads();

    // --- S = segsum relu(msg@W1+b1); thread (col,q) -> agent q ---
    {
        float w1[ORIG];
#pragma unroll
        for (int c = 0; c < ORIG; ++c) w1[c] = enc_W1[c * EMBED + col];
        const float b1 = enc_b1[col];
        float acc = 0.f;
#pragma unroll
        for (int d = 0; d < OBSD; ++d) {
            const int r = q * OBSD + d;
            const float4* mr = (const float4*)&msg[r][0];
            const float4 m0 = mr[0], m1 = mr[1], m2 = mr[2], m3 = mr[3];
            const float2 m4 = *(const float2*)&msg[r][16];
            float h = b1
                + m0.x*w1[0]  + m0.y*w1[1]  + m0.z*w1[2]  + m0.w*w1[3]
                + m1.x*w1[4]  + m1.y*w1[5]  + m1.z*w1[6]  + m1.w*w1[7]
                + m2.x*w1[8]  + m2.y*w1[9]  + m2.z*w1[10] + m2.w*w1[11]
                + m3.x*w1[12] + m3.y*w1[13] + m3.z*w1[14] + m3.w*w1[15]
                + m4.x*w1[16] + m4.y*w1[17];
            acc += fmaxf(h, 0.f);
        }
        ((float*)&SG[col])[q] = acc;
    }
    __syncthreads();

    // --- elems partials from S (waves 0-4) || npred-logit partials (waves 5-7) ---
    if (tid < EP_END) {
        const int pp = tid / 144, pe = tid % 144;
        const int e0 = 2 * pe;
        float4 a0 = {0.f,0.f,0.f,0.f}, a1 = {0.f,0.f,0.f,0.f};
        const int c0 = 64 * pp;
#pragma unroll 8
        for (int c = c0; c < c0 + 64; ++c) {
            const float4 s = SG[c];
            const float2 w2 = *(const float2*)&fWxA[c * EL + e0];
            a0.x += s.x*w2.x; a0.y += s.y*w2.x; a0.z += s.z*w2.x; a0.w += s.w*w2.x;
            a1.x += s.x*w2.y; a1.y += s.y*w2.y; a1.z += s.z*w2.y; a1.w += s.w*w2.y;
        }
        Pp[pp][e0] = a0; Pp[pp][e0 + 1] = a1;
    } else if (tid >= LG_BEG && tid < LG_END) {
        const int lu = tid - LG_BEG, pp = lu / 68, lq = lu % 68;
        const int g = lq / NQ, qq = lq % NQ;
        float v = 0.f;
        const int c0 = 64 * pp;
#pragma unroll 8
        for (int c = c0; c < c0 + 64; ++c)
            v += ((const float*)&SG[c])[g] * fWsA[c * NQ + qq];
        Lp[pp][lq] = v;
    }
    __syncthreads();

    if (tid < EL) {
        const float4 a = Pp[0][tid], b = Pp[1][tid];
        const float bx = fbxA[tid];
        elems_base[(size_t)(i0 + 0) * EL + tid] = a.x + b.x + bx;
        elems_base[(size_t)(i0 + 1) * EL + tid] = a.y + b.y + bx;
        elems_base[(size_t)(i0 + 2) * EL + tid] = a.z + b.z + bx;
        elems_base[(size_t)(i0 + 3) * EL + tid] = a.w + b.w + bx;
    } else if (tid < EL + G * NQ) {
        const int lq = tid - EL;
        const int g = lq / NQ, qq = lq % NQ;
        lgts[g][qq] = Lp[0][lq] + Lp[1][lq] + fbsA[qq];
    } else if (tid < EL + G * NQ + G * MAXO) {
        // coalesced positions side-array: pxy_base[(i0+g)*16+m] = elems cols 16,17
        const int u = tid - (EL + G * NQ);
        const int g = u >> 4, m = u & 15;
        const int e16 = m * ORIG + 16, e17 = e16 + 1;
        const float px = ((const float*)&Pp[0][e16])[g] + ((const float*)&Pp[1][e16])[g]
                       + fbxA[e16];
        const float py = ((const float*)&Pp[0][e17])[g] + ((const float*)&Pp[1][e17])[g]
                       + fbxA[e17];
        pxy_base[(size_t)(i0 + g) * MAXO + m] = make_float2(px, py);
    }
    __syncthreads();
    if (tid < G) {
        int best = 0; float bv = lgts[tid][0];
        for (int qq = 1; qq < NQ; ++qq) if (lgts[tid][qq] > bv) { bv = lgts[tid][qq]; best = qq; }
        npred_out[i0 + tid] = best;
    }
}

// ---------------------------------------------------------------------------
// Kernel B: 4 target agents, 512 threads; wave-pair per agent for
// compaction/dedup (2-wide vectorized scan); hsum -> direct fused decode.
// ---------------------------------------------------------------------------
__global__ __launch_bounds__(NTHR, 8) void merge512_kernel(
    const float* __restrict__ agent_pos,
    const float* __restrict__ menc_W1, const float* __restrict__ menc_b1,
    const float* __restrict__ fWxB, const float* __restrict__ fbxB,
    const float* __restrict__ fWsB, const float* __restrict__ fbsB,
    const int* __restrict__ comm_edge,
    const float* __restrict__ elems_base, const int* __restrict__ npred,
    const float2* __restrict__ pxy_base,
    float* __restrict__ out_dec, float* __restrict__ out_batch,
    float* __restrict__ out_mask)
{
    const int blk = blockIdx.x, tid = threadIdx.x;
    const int i0  = blk * G;
    const int col = tid & 127, q = tid >> 7;
    const int lane = tid & 63, wv = tid >> 6;
    const int w = wv >> 1, half = wv & 1;

    __shared__ int    jn[G][DEG];
    __shared__ float  relx[G][DEG], rely[G][DEG];
    __shared__ int    npd[G][DEG];
    __shared__ float2 pxy[G][KCAND];
    __shared__ int    vl[G][KCAND + 2];  // compacted valid indices + sentinels
    __shared__ float2 pv[G][KCAND];      // compacted valid positions
    __shared__ int    wcv[G][2], kcv[G][2];
    __shared__ int    nv[G], kcnt[G];
    __shared__ int    klist[G][MAXO];
    __shared__ float  kc[G][MAXO][20];
    __shared__ float4 Hs[EMBED];
    __shared__ float  Lp[2][G * NQ];
    __shared__ float  lg2[G][NQ];
    __shared__ int    n2s[G];
    __shared__ float4 Pp[2][EL];

    if (tid < G * DEG) {
        const int g = tid >> 3, d = tid & 7;
        const int e = (i0 + g) * DEG + d;
        const int j  = comm_edge[e];
        const int ii = comm_edge[A_N * DEG + e];
        jn[g][d]  = j;
        relx[g][d] = agent_pos[j * 2 + 0] - agent_pos[ii * 2 + 0];
        rely[g][d] = agent_pos[j * 2 + 1] - agent_pos[ii * 2 + 1];
        npd[g][d] = npred[j];
    }
    __syncthreads();

    // --- positions (coalesced) + valid, compacted list + sentinels ---
    const int k = 64 * half + lane;
    const int kd = k >> 4, km = k & 15;
    float2 p;
    int val;
    {
        p = pxy_base[(size_t)jn[w][kd] * MAXO + km];
        p.x += relx[w][kd]; p.y += rely[w][kd];
        pxy[w][k] = p;
        val = (km < npd[w][kd]) ? 1 : 0;
        const unsigned long long bal = __ballot(val);
        const int pref = (int)__popcll(bal << (63 - lane));
        if (lane == 63) wcv[w][half] = (int)__popcll(bal);
        __syncthreads();
        const int base = half ? wcv[w][0] : 0;
        if (val) { vl[w][base + pref - 1] = k; pv[w][base + pref - 1] = p; }
        if (lane == 0 && half == 0) {
            const int tot = wcv[w][0] + wcv[w][1];
            nv[w] = tot;
            vl[w][tot] = 0x7fffffff;         // sentinels for 2-wide scan
            vl[w][tot + 1] = 0x7fffffff;
        }
        __syncthreads();
    }

    // --- dedup + cap 15: 2-wide vectorized scan of compacted streams ---
    {
        const int nvg = nv[w];
        int dup = 0;
        for (int idx = 0; idx < nvg; idx += 2) {
            const int2   kk = *(const int2*)&vl[w][idx];
            const float4 pq = *(const float4*)&pv[w][idx];
            if (kk.x >= k) break;
            float dx = pq.x - p.x, dy = pq.y - p.y;
            dup |= (dx * dx + dy * dy < THRES2) ? 1 : 0;
            if (kk.y >= k) break;
            dx = pq.z - p.x; dy = pq.w - p.y;
            dup |= (dx * dx + dy * dy < THRES2) ? 1 : 0;
        }
        const int kp = (val && !dup) ? 1 : 0;
        const unsigned long long bal = __ballot(kp);
        const int pref = (int)__popcll(bal << (63 - lane));
        if (lane == 63) kcv[w][half] = (int)__popcll(bal);
        __syncthreads();
        const int cnt = (half ? kcv[w][0] : 0) + pref;
        if (kp && cnt <= MAXO - 1) klist[w][cnt - 1] = k;
        if (lane == 0 && half == 0) {
            const int tot = kcv[w][0] + kcv[w][1];
            kcnt[w] = (tot < MAXO - 1) ? tot : (MAXO - 1);
        }
        __syncthreads();
    }

    // --- gather kept rows ---
    for (int idx = tid; idx < G * EL; idx += NTHR) {
        const int g = idx / EL, rem = idx % EL;
        const int s = rem / ORIG, c = rem % ORIG;
        if (s < kcnt[g]) {
            const int kk = klist[g][s], d = kk >> 4, m = kk & 15;
            float v;
            if (c < 16) v = elems_base[(size_t)jn[g][d] * EL + m * ORIG + c];
            else        v = (c == 16) ? pxy[g][kk].x : pxy[g][kk].y;
            kc[g][s][c] = v;
        }
    }
    __syncthreads();

    // --- hsum: thread (col,q) -> agent q over <=15 kept rows ---
    {
        float w1[ORIG];
#pragma unroll
        for (int c = 0; c < ORIG; ++c) w1[c] = menc_W1[c * EMBED + col];
        const float b1 = menc_b1[col];
        const int nk = kcnt[q];
        float hs = 0.f;
        for (int s = 0; s < nk; ++s) {
            const float4* mr = (const float4*)&kc[q][s][0];
            const float4 m0 = mr[0], m1 = mr[1], m2 = mr[2], m3 = mr[3];
            const float2 m4 = *(const float2*)&kc[q][s][16];
            float h = b1
                + m0.x*w1[0]  + m0.y*w1[1]  + m0.z*w1[2]  + m0.w*w1[3]
                + m1.x*w1[4]  + m1.y*w1[5]  + m1.z*w1[6]  + m1.w*w1[7]
                + m2.x*w1[8]  + m2.y*w1[9]  + m2.z*w1[10] + m2.w*w1[11]
                + m3.x*w1[12] + m3.y*w1[13] + m3.z*w1[14] + m3.w*w1[15]
                + m4.x*w1[16] + m4.y*w1[17];
            hs += fmaxf(h, 0.f);
        }
        ((float*)&Hs[col])[q] = hs;
    }
    __syncthreads();

    // --- decode partials from Hs (waves 0-4) || n2-logit partials (waves 5-7) ---
    if (tid < EP_END) {
        const int pp = tid / 144, pe = tid % 144;
        const int e0 = 2 * pe;
        float4 a0 = {0.f,0.f,0.f,0.f}, a1 = {0.f,0.f,0.f,0.f};
        const int c0 = 64 * pp;
#pragma unroll 8
        for (int c = c0; c < c0 + 64; ++c) {
            const float4 s = Hs[c];
            const float2 w2 = *(const float2*)&fWxB[c * EL + e0];
            a0.x += s.x*w2.x; a0.y += s.y*w2.x; a0.z += s.z*w2.x; a0.w += s.w*w2.x;
            a1.x += s.x*w2.y; a1.y += s.y*w2.y; a1.z += s.z*w2.y; a1.w += s.w*w2.y;
        }
        Pp[pp][e0] = a0; Pp[pp][e0 + 1] = a1;
    } else if (tid >= LG_BEG && tid < LG_END) {
        const int lu = tid - LG_BEG, pp = lu / 68, lq = lu % 68;
        const int g = lq / NQ, qq = lq % NQ;
        float v = 0.f;
        const int c0 = 64 * pp;
#pragma unroll 8
        for (int c = c0; c < c0 + 64; ++c)
            v += ((const float*)&Hs[c])[g] * fWsB[c * NQ + qq];
        Lp[pp][lq] = v;
    }
    __syncthreads();

    // decode combine into registers (no n2 dependency) || logit combine
    float4 dreg = {0.f, 0.f, 0.f, 0.f};
    if (tid < EL) {
        const float4 a = Pp[0][tid], b = Pp[1][tid];
        const float bx = fbxB[tid];
        dreg.x = a.x + b.x + bx; dreg.y = a.y + b.y + bx;
        dreg.z = a.z + b.z + bx; dreg.w = a.w + b.w + bx;
    } else if (tid < EL + G * NQ) {
        const int lq = tid - EL;
        const int g = lq / NQ, qq = lq % NQ;
        lg2[g][qq] = Lp[0][lq] + Lp[1][lq] + fbsB[qq];
    }
    __syncthreads();
    if (tid < G) {
        int best = 0; float bv = lg2[tid][0];
        for (int qq = 1; qq < NQ; ++qq) if (lg2[tid][qq] > bv) { bv = lg2[tid][qq]; best = qq; }
        n2s[tid] = best;
    }
    __syncthreads();

    if (tid < EL) {
        const int m = tid / ORIG;
        out_dec[(size_t)(i0 + 0) * EL + tid] = (m < n2s[0]) ? dreg.x : 0.f;
        out_dec[(size_t)(i0 + 1) * EL + tid] = (m < n2s[1]) ? dreg.y : 0.f;
        out_dec[(size_t)(i0 + 2) * EL + tid] = (m < n2s[2]) ? dreg.z : 0.f;
        out_dec[(size_t)(i0 + 3) * EL + tid] = (m < n2s[3]) ? dreg.w : 0.f;
    } else if (tid >= NTHR - G * MAXO) {
        const int idx = tid - (NTHR - G * MAXO);
        const int g = idx >> 4, m = idx & 15;
        out_batch[(i0 + g) * MAXO + m] = (float)(i0 + g);
        out_mask[(i0 + g) * MAXO + m]  = (m < n2s[g]) ? 1.f : 0.f;
    }
}

extern "C" void kernel_launch(void* const* d_in, const int* in_sizes, int n_in,
                              void* d_out, int out_size, void* d_ws, size_t ws_size,
                              hipStream_t stream)
{
    const float* obj_x     = (const float*)d_in[0];
    const float* obj_pos   = (const float*)d_in[1];
    const float* agent_pos = (const float*)d_in[2];
    const float* enc_W1    = (const float*)d_in[3];
    const float* enc_b1    = (const float*)d_in[4];
    const float* enc_W2    = (const float*)d_in[5];
    const float* enc_b2    = (const float*)d_in[6];
    const float* mdec_Ws   = (const float*)d_in[7];
    const float* mdec_bs   = (const float*)d_in[8];
    const float* mdec_Wx   = (const float*)d_in[9];
    const float* mdec_bx   = (const float*)d_in[10];
    const float* menc_W1   = (const float*)d_in[11];
    const float* menc_b1   = (const float*)d_in[12];
    const float* menc_W2   = (const float*)d_in[13];
    const float* menc_b2   = (const float*)d_in[14];
    const float* dec_Ws    = (const float*)d_in[15];
    const float* dec_bs    = (const float*)d_in[16];
    const float* dec_Wx    = (const float*)d_in[17];
    const float* dec_bx    = (const float*)d_in[18];
    const int*   obs_edge  = (const int*)d_in[19];
    const int*   comm_edge = (const int*)d_in[20];

    char* ws = (char*)d_ws;
    size_t off = 0;
    float*  elems_base = (float*)(ws + off);  off += (size_t)A_N * EL * sizeof(float);
    int*    npred      = (int*)(ws + off);    off += (size_t)A_N * sizeof(int);
    float2* pxy_base   = (float2*)(ws + off); off += (size_t)A_N * MAXO * sizeof(float2);
    float*  fWxA = (float*)(ws + off);        off += (size_t)EMBED * EL * sizeof(float);
    float*  fbxA = (float*)(ws + off);        off += (size_t)EL * sizeof(float);
    float*  fWsA = (float*)(ws + off);        off += (size_t)EMBED * NQ * sizeof(float);
    float*  fbsA = (float*)(ws + off);        off += 32 * sizeof(float);
    float*  fWxB = (float*)(ws + off);        off += (size_t)EMBED * EL * sizeof(float);
    float*  fbxB = (float*)(ws + off);        off += (size_t)EL * sizeof(float);
    float*  fWsB = (float*)(ws + off);        off += (size_t)EMBED * NQ * sizeof(float);
    float*  fbsB = (float*)(ws + off);        off += 32 * sizeof(float);

    float* out_dec   = (float*)d_out;
    float* out_batch = out_dec + (size_t)A_N * EL;
    float* out_mask  = out_batch + (size_t)A_N * MAXO;

    prep_kernel<<<258, 320, 0, stream>>>(
        enc_W2, enc_b2, mdec_Wx, mdec_Ws, mdec_bx, mdec_bs,
        menc_W2, menc_b2, dec_Wx, dec_Ws, dec_bx, dec_bs,
        fWxA, fbxA, fWsA, fbsA, fWxB, fbxB, fWsB, fbsB);

    enc512_kernel<<<NBLK, NTHR, 0, stream>>>(
        obj_x, obj_pos, agent_pos, enc_W1, enc_b1,
        fWxA, fbxA, fWsA, fbsA, obs_edge,
        elems_base, npred, pxy_base);

    merge512_kernel<<<NBLK, NTHR, 0, stream>>>(
        agent_pos, menc_W1, menc_b1,
        fWxB, fbxB, fWsB, fbsB, comm_edge,
        elems_base, npred, pxy_base, out_dec, out_batch, out_mask);
}

// Round 12
// 152.533 us; speedup vs baseline: 1.0330x; 1.0330x over previous
//
#include <hip/hip_runtime.h>

#define A_N   4096
#define EMBED 128
#define MAXO  16
#define DEG   8
#define OBSD  8
#define ORIG  18
#define KCAND 128            // DEG*MAXO candidates per agent
#define G     4              // agents per block
#define NBLK  (A_N / G)      // 1024 blocks
#define NTHR  512            // 8 waves/block -> 4 blocks/CU = 32 waves/CU
#define EL    (MAXO * ORIG)  // 288
#define NQ    (MAXO + 1)     // 17
#define THRES2 (0.02f * 0.02f)

// ---------------------------------------------------------------------------
// Prep: fuse linear chains through W2 (runs every call; ~20 MFLOP):
//   A: fWxA = enc_W2@mdec_Wx,  fbxA = enc_b2@mdec_Wx + mdec_bx
//      fWsA = enc_W2@mdec_Ws,  fbsA = enc_b2@mdec_Ws + mdec_bs
//   B: same with menc_W2/menc_b2, dec_*.
// ---------------------------------------------------------------------------
__global__ __launch_bounds__(320) void prep_kernel(
    const float* __restrict__ enc_W2, const float* __restrict__ enc_b2,
    const float* __restrict__ mdec_Wx, const float* __restrict__ mdec_Ws,
    const float* __restrict__ mdec_bx, const float* __restrict__ mdec_bs,
    const float* __restrict__ menc_W2, const float* __restrict__ menc_b2,
    const float* __restrict__ dec_Wx, const float* __restrict__ dec_Ws,
    const float* __restrict__ dec_bx, const float* __restrict__ dec_bs,
    float* __restrict__ fWxA, float* __restrict__ fbxA,
    float* __restrict__ fWsA, float* __restrict__ fbsA,
    float* __restrict__ fWxB, float* __restrict__ fbxB,
    float* __restrict__ fWsB, float* __restrict__ fbsB)
{
    const int b = blockIdx.x, tid = threadIdx.x;
    const int side = b / 129, r = b % 129;
    const float* W2 = side ? menc_W2 : enc_W2;
    const float* b2 = side ? menc_b2 : enc_b2;
    const float* Wx = side ? dec_Wx : mdec_Wx;
    const float* Ws = side ? dec_Ws : mdec_Ws;
    const float* bx = side ? dec_bx : mdec_bx;
    const float* bs = side ? dec_bs : mdec_bs;
    float* oWx = side ? fWxB : fWxA;
    float* obx = side ? fbxB : fbxA;
    float* oWs = side ? fWsB : fWsA;
    float* obs_ = side ? fbsB : fbsA;

    __shared__ float rv[EMBED];
    if (tid < EMBED) rv[tid] = (r < EMBED) ? W2[r * EMBED + tid] : b2[tid];
    __syncthreads();

    if (tid < EL) {
        float acc = 0.f;
        for (int t = 0; t < EMBED; ++t) acc += rv[t] * Wx[t * EL + tid];
        if (r < EMBED) oWx[r * EL + tid] = acc;
        else           obx[tid] = acc + bx[tid];
    } else if (tid < EL + NQ) {
        const int q = tid - EL;
        float acc = 0.f;
        for (int t = 0; t < EMBED; ++t) acc += rv[t] * Ws[t * NQ + q];
        if (r < EMBED) oWs[r * NQ + q] = acc;
        else           obs_[q] = acc + bs[q];
    }
}

// ---------------------------------------------------------------------------
// Kernel A: 4 source agents, 512 threads. Phases (all-threads-busy style):
// msg -> segsum S -> elems 576-unit splitK2 GEMV (S@fWxA) -> npred-logit
// splitK4 (272 thr) -> combine(elems+pxy+logits) -> argmax.
// ---------------------------------------------------------------------------
__global__ __launch_bounds__(NTHR, 8) void enc512_kernel(
    const float* __restrict__ obj_x, const float* __restrict__ obj_pos,
    const float* __restrict__ agent_pos,
    const float* __restrict__ enc_W1, const float* __restrict__ enc_b1,
    const float* __restrict__ fWxA, const float* __restrict__ fbxA,
    const float* __restrict__ fWsA, const float* __restrict__ fbsA,
    const int* __restrict__ obs_edge,
    float* __restrict__ elems_base, int* __restrict__ npred_out,
    float2* __restrict__ pxy_base)
{
    const int blk = blockIdx.x, tid = threadIdx.x;
    const int i0  = blk * G;
    const int col = tid & 127, q = tid >> 7;

    __shared__ int    on[G][OBSD];
    __shared__ float  msg[G * OBSD][20];
    __shared__ float4 SG[EMBED];          // segsum, [c] -> 4 agents
    __shared__ float  Lp[4][G * NQ];      // logit split-K4 partials
    __shared__ float  lgts[G][NQ];
    __shared__ float4 Pp[2][EL];          // elems split-K2 partials

    if (tid < G * OBSD) {
        const int g = tid >> 3, d = tid & 7;
        on[g][d] = obs_edge[A_N * OBSD + (i0 + g) * OBSD + d];
    }
    __syncthreads();
    for (int idx = tid; idx < G * OBSD * ORIG; idx += NTHR) {
        const int r = idx / ORIG, c = idx % ORIG;
        const int g = r >> 3, d = r & 7;
        const int o = on[g][d];
        float v;
        if (c < 16) v = obj_x[o * 16 + c];
        else        v = obj_pos[o * 2 + (c - 16)] - agent_pos[(i0 + g) * 2 + (c - 16)];
        msg[r][c] = v;
    }
    __syncthreads();

    // --- S = segsum relu(msg@W1+b1); thread (col,q) -> agent q ---
    {
        float w1[ORIG];
#pragma unroll
        for (int c = 0; c < ORIG; ++c) w1[c] = enc_W1[c * EMBED + col];
        const float b1 = enc_b1[col];
        float acc = 0.f;
#pragma unroll
        for (int d = 0; d < OBSD; ++d) {
            const int r = q * OBSD + d;
            const float4* mr = (const float4*)&msg[r][0];
            const float4 m0 = mr[0], m1 = mr[1], m2 = mr[2], m3 = mr[3];
            const float2 m4 = *(const float2*)&msg[r][16];
            float h = b1
                + m0.x*w1[0]  + m0.y*w1[1]  + m0.z*w1[2]  + m0.w*w1[3]
                + m1.x*w1[4]  + m1.y*w1[5]  + m1.z*w1[6]  + m1.w*w1[7]
                + m2.x*w1[8]  + m2.y*w1[9]  + m2.z*w1[10] + m2.w*w1[11]
                + m3.x*w1[12] + m3.y*w1[13] + m3.z*w1[14] + m3.w*w1[15]
                + m4.x*w1[16] + m4.y*w1[17];
            acc += fmaxf(h, 0.f);
        }
        ((float*)&SG[col])[q] = acc;
    }
    __syncthreads();

    // --- elems partials from S: 576 units over 512 threads (all busy) ---
    {
        int u = tid;
        for (int pass = 0; pass < 2; ++pass) {
            if (u < 2 * EL) {
                const int h = (u >= EL) ? 1 : 0;
                const int e = u - h * EL;
                float4 acc = {0.f, 0.f, 0.f, 0.f};
                const int c0 = 64 * h;
#pragma unroll 8
                for (int c = c0; c < c0 + 64; ++c) {
                    const float4 s = SG[c];
                    const float  w = fWxA[c * EL + e];
                    acc.x += s.x * w; acc.y += s.y * w; acc.z += s.z * w; acc.w += s.w * w;
                }
                Pp[h][e] = acc;
            }
            u = NTHR + tid;      // second pass: units 512..575 (tid<64)
        }
    }
    __syncthreads();

    // --- npred logit partials from S: split-K4 over 272 threads ---
    {
        const int p = tid >> 7, rem = tid & 127;
        if (rem < G * NQ) {
            const int g = rem / NQ, qq = rem % NQ;
            float v = 0.f;
            const int c0 = 32 * p;
#pragma unroll 8
            for (int c = c0; c < c0 + 32; ++c)
                v += ((const float*)&SG[c])[g] * fWsA[c * NQ + qq];
            Lp[p][rem] = v;
        }
    }
    __syncthreads();

    // --- combine: elems write || pxy_base || logit combine ---
    if (tid < EL) {
        const float4 a = Pp[0][tid], b = Pp[1][tid];
        const float bx = fbxA[tid];
        elems_base[(size_t)(i0 + 0) * EL + tid] = a.x + b.x + bx;
        elems_base[(size_t)(i0 + 1) * EL + tid] = a.y + b.y + bx;
        elems_base[(size_t)(i0 + 2) * EL + tid] = a.z + b.z + bx;
        elems_base[(size_t)(i0 + 3) * EL + tid] = a.w + b.w + bx;
    } else if (tid < EL + G * MAXO) {
        const int u = tid - EL;
        const int g = u >> 4, m = u & 15;
        const int e16 = m * ORIG + 16, e17 = e16 + 1;
        const float px = ((const float*)&Pp[0][e16])[g] + ((const float*)&Pp[1][e16])[g]
                       + fbxA[e16];
        const float py = ((const float*)&Pp[0][e17])[g] + ((const float*)&Pp[1][e17])[g]
                       + fbxA[e17];
        pxy_base[(size_t)(i0 + g) * MAXO + m] = make_float2(px, py);
    } else if (tid < EL + G * MAXO + G * NQ) {
        const int lq = tid - (EL + G * MAXO);
        const int g = lq / NQ, qq = lq % NQ;
        lgts[g][qq] = Lp[0][lq] + Lp[1][lq] + Lp[2][lq] + Lp[3][lq] + fbsA[qq];
    }
    __syncthreads();
    if (tid < G) {
        int best = 0; float bv = lgts[tid][0];
        for (int qq = 1; qq < NQ; ++qq) if (lgts[tid][qq] > bv) { bv = lgts[tid][qq]; best = qq; }
        npred_out[i0 + tid] = best;
    }
}

// ---------------------------------------------------------------------------
// Kernel B: 4 target agents, 512 threads; wave-pair per agent for
// compaction/dedup (2-wide scan); hsum -> fused decode (576-unit) ->
// fused n2 logits (split-K4) -> combine -> masked write.
// ---------------------------------------------------------------------------
__global__ __launch_bounds__(NTHR, 8) void merge512_kernel(
    const float* __restrict__ agent_pos,
    const float* __restrict__ menc_W1, const float* __restrict__ menc_b1,
    const float* __restrict__ fWxB, const float* __restrict__ fbxB,
    const float* __restrict__ fWsB, const float* __restrict__ fbsB,
    const int* __restrict__ comm_edge,
    const float* __restrict__ elems_base, const int* __restrict__ npred,
    const float2* __restrict__ pxy_base,
    float* __restrict__ out_dec, float* __restrict__ out_batch,
    float* __restrict__ out_mask)
{
    const int blk = blockIdx.x, tid = threadIdx.x;
    const int i0  = blk * G;
    const int col = tid & 127, q = tid >> 7;
    const int lane = tid & 63, wv = tid >> 6;
    const int w = wv >> 1, half = wv & 1;

    __shared__ int    jn[G][DEG];
    __shared__ float  relx[G][DEG], rely[G][DEG];
    __shared__ int    npd[G][DEG];
    __shared__ float2 pxy[G][KCAND];
    __shared__ __align__(8)  int    vl[G][KCAND + 2];  // compacted idx + sentinels
    __shared__ __align__(16) float2 pv[G][KCAND];      // compacted positions
    __shared__ int    wcv[G][2], kcv[G][2];
    __shared__ int    nv[G], kcnt[G];
    __shared__ int    klist[G][MAXO];
    __shared__ float  kc[G][MAXO][20];
    __shared__ float4 Hs[EMBED];
    __shared__ float  Lp[4][G * NQ];
    __shared__ float  lg2[G][NQ];
    __shared__ int    n2s[G];
    __shared__ float4 Pp[2][EL];

    if (tid < G * DEG) {
        const int g = tid >> 3, d = tid & 7;
        const int e = (i0 + g) * DEG + d;
        const int j  = comm_edge[e];
        const int ii = comm_edge[A_N * DEG + e];
        jn[g][d]  = j;
        relx[g][d] = agent_pos[j * 2 + 0] - agent_pos[ii * 2 + 0];
        rely[g][d] = agent_pos[j * 2 + 1] - agent_pos[ii * 2 + 1];
        npd[g][d] = npred[j];
    }
    __syncthreads();

    // --- positions (coalesced) + valid, compacted list + sentinels ---
    const int k = 64 * half + lane;
    const int kd = k >> 4, km = k & 15;
    float2 p;
    int val;
    {
        p = pxy_base[(size_t)jn[w][kd] * MAXO + km];
        p.x += relx[w][kd]; p.y += rely[w][kd];
        pxy[w][k] = p;
        val = (km < npd[w][kd]) ? 1 : 0;
        const unsigned long long bal = __ballot(val);
        const int pref = (int)__popcll(bal << (63 - lane));
        if (lane == 63) wcv[w][half] = (int)__popcll(bal);
        __syncthreads();
        const int base = half ? wcv[w][0] : 0;
        if (val) { vl[w][base + pref - 1] = k; pv[w][base + pref - 1] = p; }
        if (lane == 0 && half == 0) {
            const int tot = wcv[w][0] + wcv[w][1];
            nv[w] = tot;
            vl[w][tot] = 0x7fffffff;         // sentinels for 2-wide scan
            vl[w][tot + 1] = 0x7fffffff;
        }
        __syncthreads();
    }

    // --- dedup + cap 15: 2-wide vectorized scan of compacted streams ---
    {
        const int nvg = nv[w];
        int dup = 0;
        for (int idx = 0; idx < nvg; idx += 2) {
            const int2   kk = *(const int2*)&vl[w][idx];
            const float4 pq = *(const float4*)&pv[w][idx];
            if (kk.x >= k) break;
            float dx = pq.x - p.x, dy = pq.y - p.y;
            dup |= (dx * dx + dy * dy < THRES2) ? 1 : 0;
            if (kk.y >= k) break;
            dx = pq.z - p.x; dy = pq.w - p.y;
            dup |= (dx * dx + dy * dy < THRES2) ? 1 : 0;
        }
        const int kp = (val && !dup) ? 1 : 0;
        const unsigned long long bal = __ballot(kp);
        const int pref = (int)__popcll(bal << (63 - lane));
        if (lane == 63) kcv[w][half] = (int)__popcll(bal);
        __syncthreads();
        const int cnt = (half ? kcv[w][0] : 0) + pref;
        if (kp && cnt <= MAXO - 1) klist[w][cnt - 1] = k;
        if (lane == 0 && half == 0) {
            const int tot = kcv[w][0] + kcv[w][1];
            kcnt[w] = (tot < MAXO - 1) ? tot : (MAXO - 1);
        }
        __syncthreads();
    }

    // --- gather kept rows ---
    for (int idx = tid; idx < G * EL; idx += NTHR) {
        const int g = idx / EL, rem = idx % EL;
        const int s = rem / ORIG, c = rem % ORIG;
        if (s < kcnt[g]) {
            const int kk = klist[g][s], d = kk >> 4, m = kk & 15;
            float v;
            if (c < 16) v = elems_base[(size_t)jn[g][d] * EL + m * ORIG + c];
            else        v = (c == 16) ? pxy[g][kk].x : pxy[g][kk].y;
            kc[g][s][c] = v;
        }
    }
    __syncthreads();

    // --- hsum: thread (col,q) -> agent q over <=15 kept rows ---
    {
        float w1[ORIG];
#pragma unroll
        for (int c = 0; c < ORIG; ++c) w1[c] = menc_W1[c * EMBED + col];
        const float b1 = menc_b1[col];
        const int nk = kcnt[q];
        float hs = 0.f;
        for (int s = 0; s < nk; ++s) {
            const float4* mr = (const float4*)&kc[q][s][0];
            const float4 m0 = mr[0], m1 = mr[1], m2 = mr[2], m3 = mr[3];
            const float2 m4 = *(const float2*)&kc[q][s][16];
            float h = b1
                + m0.x*w1[0]  + m0.y*w1[1]  + m0.z*w1[2]  + m0.w*w1[3]
                + m1.x*w1[4]  + m1.y*w1[5]  + m1.z*w1[6]  + m1.w*w1[7]
                + m2.x*w1[8]  + m2.y*w1[9]  + m2.z*w1[10] + m2.w*w1[11]
                + m3.x*w1[12] + m3.y*w1[13] + m3.z*w1[14] + m3.w*w1[15]
                + m4.x*w1[16] + m4.y*w1[17];
            hs += fmaxf(h, 0.f);
        }
        ((float*)&Hs[col])[q] = hs;
    }
    __syncthreads();

    // --- decode partials from Hs: 576 units over 512 threads (all busy) ---
    {
        int u = tid;
        for (int pass = 0; pass < 2; ++pass) {
            if (u < 2 * EL) {
                const int h = (u >= EL) ? 1 : 0;
                const int e = u - h * EL;
                float4 acc = {0.f, 0.f, 0.f, 0.f};
                const int c0 = 64 * h;
#pragma unroll 8
                for (int c = c0; c < c0 + 64; ++c) {
                    const float4 s = Hs[c];
                    const float  ww = fWxB[c * EL + e];
                    acc.x += s.x * ww; acc.y += s.y * ww; acc.z += s.z * ww; acc.w += s.w * ww;
                }
                Pp[h][e] = acc;
            }
            u = NTHR + tid;
        }
    }
    __syncthreads();

    // --- n2 logit partials from Hs: split-K4 over 272 threads ---
    {
        const int pth = tid >> 7, rem = tid & 127;
        if (rem < G * NQ) {
            const int g = rem / NQ, qq = rem % NQ;
            float v = 0.f;
            const int c0 = 32 * pth;
#pragma unroll 8
            for (int c = c0; c < c0 + 32; ++c)
                v += ((const float*)&Hs[c])[g] * fWsB[c * NQ + qq];
            Lp[pth][rem] = v;
        }
    }
    __syncthreads();

    // --- combine: decode into registers || logit combine ---
    float4 dreg = {0.f, 0.f, 0.f, 0.f};
    if (tid < EL) {
        const float4 a = Pp[0][tid], b = Pp[1][tid];
        const float bx = fbxB[tid];
        dreg.x = a.x + b.x + bx; dreg.y = a.y + b.y + bx;
        dreg.z = a.z + b.z + bx; dreg.w = a.w + b.w + bx;
    } else if (tid < EL + G * NQ) {
        const int lq = tid - EL;
        const int g = lq / NQ, qq = lq % NQ;
        lg2[g][qq] = Lp[0][lq] + Lp[1][lq] + Lp[2][lq] + Lp[3][lq] + fbsB[qq];
    }
    __syncthreads();
    if (tid < G) {
        int best = 0; float bv = lg2[tid][0];
        for (int qq = 1; qq < NQ; ++qq) if (lg2[tid][qq] > bv) { bv = lg2[tid][qq]; best = qq; }
        n2s[tid] = best;
    }
    __syncthreads();

    if (tid < EL) {
        const int m = tid / ORIG;
        out_dec[(size_t)(i0 + 0) * EL + tid] = (m < n2s[0]) ? dreg.x : 0.f;
        out_dec[(size_t)(i0 + 1) * EL + tid] = (m < n2s[1]) ? dreg.y : 0.f;
        out_dec[(size_t)(i0 + 2) * EL + tid] = (m < n2s[2]) ? dreg.z : 0.f;
        out_dec[(size_t)(i0 + 3) * EL + tid] = (m < n2s[3]) ? dreg.w : 0.f;
    } else if (tid >= NTHR - G * MAXO) {
        const int idx = tid - (NTHR - G * MAXO);
        const int g = idx >> 4, m = idx & 15;
        out_batch[(i0 + g) * MAXO + m] = (float)(i0 + g);
        out_mask[(i0 + g) * MAXO + m]  = (m < n2s[g]) ? 1.f : 0.f;
    }
}

extern "C" void kernel_launch(void* const* d_in, const int* in_sizes, int n_in,
                              void* d_out, int out_size, void* d_ws, size_t ws_size,
                              hipStream_t stream)
{
    const float* obj_x     = (const float*)d_in[0];
    const float* obj_pos   = (const float*)d_in[1];
    const float* agent_pos = (const float*)d_in[2];
    const float* enc_W1    = (const float*)d_in[3];
    const float* enc_b1    = (const float*)d_in[4];
    const float* enc_W2    = (const float*)d_in[5];
    const float* enc_b2    = (const float*)d_in[6];
    const float* mdec_Ws   = (const float*)d_in[7];
    const float* mdec_bs   = (const float*)d_in[8];
    const float* mdec_Wx   = (const float*)d_in[9];
    const float* mdec_bx   = (const float*)d_in[10];
    const float* menc_W1   = (const float*)d_in[11];
    const float* menc_b1   = (const float*)d_in[12];
    const float* menc_W2   = (const float*)d_in[13];
    const float* menc_b2   = (const float*)d_in[14];
    const float* dec_Ws    = (const float*)d_in[15];
    const float* dec_bs    = (const float*)d_in[16];
    const float* dec_Wx    = (const float*)d_in[17];
    const float* dec_bx    = (const float*)d_in[18];
    const int*   obs_edge  = (const int*)d_in[19];
    const int*   comm_edge = (const int*)d_in[20];

    char* ws = (char*)d_ws;
    size_t off = 0;
    float*  elems_base = (float*)(ws + off);  off += (size_t)A_N * EL * sizeof(float);
    int*    npred      = (int*)(ws + off);    off += (size_t)A_N * sizeof(int);
    float2* pxy_base   = (float2*)(ws + off); off += (size_t)A_N * MAXO * sizeof(float2);
    float*  fWxA = (float*)(ws + off);        off += (size_t)EMBED * EL * sizeof(float);
    float*  fbxA = (float*)(ws + off);        off += (size_t)EL * sizeof(float);
    float*  fWsA = (float*)(ws + off);        off += (size_t)EMBED * NQ * sizeof(float);
    float*  fbsA = (float*)(ws + off);        off += 32 * sizeof(float);
    float*  fWxB = (float*)(ws + off);        off += (size_t)EMBED * EL * sizeof(float);
    float*  fbxB = (float*)(ws + off);        off += (size_t)EL * sizeof(float);
    float*  fWsB = (float*)(ws + off);        off += (size_t)EMBED * NQ * sizeof(float);
    float*  fbsB = (float*)(ws + off);        off += 32 * sizeof(float);

    float* out_dec   = (float*)d_out;
    float* out_batch = out_dec + (size_t)A_N * EL;
    float* out_mask  = out_batch + (size_t)A_N * MAXO;

    prep_kernel<<<258, 320, 0, stream>>>(
        enc_W2, enc_b2, mdec_Wx, mdec_Ws, mdec_bx, mdec_bs,
        menc_W2, menc_b2, dec_Wx, dec_Ws, dec_bx, dec_bs,
        fWxA, fbxA, fWsA, fbsA, fWxB, fbxB, fWsB, fbsB);

    enc512_kernel<<<NBLK, NTHR, 0, stream>>>(
        obj_x, obj_pos, agent_pos, enc_W1, enc_b1,
        fWxA, fbxA, fWsA, fbsA, obs_edge,
        elems_base, npred, pxy_base);

    merge512_kernel<<<NBLK, NTHR, 0, stream>>>(
        agent_pos, menc_W1, menc_b1,
        fWxB, fbxB, fWsB, fbsB, comm_edge,
        elems_base, npred, pxy_base, out_dec, out_batch, out_mask);
}

// Round 13
// 150.475 us; speedup vs baseline: 1.0471x; 1.0137x over previous
//
#include <hip/hip_runtime.h>

#define A_N   4096
#define EMBED 128
#define MAXO  16
#define DEG   8
#define OBSD  8
#define ORIG  18
#define KCAND 128            // DEG*MAXO candidates per agent
#define G     4              // agents per block
#define NBLK  (A_N / G)      // 1024 blocks
#define NTHR  512            // 8 waves/block -> 4 blocks/CU = 32 waves/CU
#define EL    (MAXO * ORIG)  // 288
#define NQ    (MAXO + 1)     // 17
#define THRES2 (0.02f * 0.02f)

// ---------------------------------------------------------------------------
// Prep: fuse linear chains through W2 (runs every call; ~20 MFLOP):
//   A: fWxA = enc_W2@mdec_Wx,  fbxA = enc_b2@mdec_Wx + mdec_bx
//      fWsA = enc_W2@mdec_Ws,  fbsA = enc_b2@mdec_Ws + mdec_bs
//   B: same with menc_W2/menc_b2, dec_*.
// ---------------------------------------------------------------------------
__global__ __launch_bounds__(320) void prep_kernel(
    const float* __restrict__ enc_W2, const float* __restrict__ enc_b2,
    const float* __restrict__ mdec_Wx, const float* __restrict__ mdec_Ws,
    const float* __restrict__ mdec_bx, const float* __restrict__ mdec_bs,
    const float* __restrict__ menc_W2, const float* __restrict__ menc_b2,
    const float* __restrict__ dec_Wx, const float* __restrict__ dec_Ws,
    const float* __restrict__ dec_bx, const float* __restrict__ dec_bs,
    float* __restrict__ fWxA, float* __restrict__ fbxA,
    float* __restrict__ fWsA, float* __restrict__ fbsA,
    float* __restrict__ fWxB, float* __restrict__ fbxB,
    float* __restrict__ fWsB, float* __restrict__ fbsB)
{
    const int b = blockIdx.x, tid = threadIdx.x;
    const int side = b / 129, r = b % 129;
    const float* W2 = side ? menc_W2 : enc_W2;
    const float* b2 = side ? menc_b2 : enc_b2;
    const float* Wx = side ? dec_Wx : mdec_Wx;
    const float* Ws = side ? dec_Ws : mdec_Ws;
    const float* bx = side ? dec_bx : mdec_bx;
    const float* bs = side ? dec_bs : mdec_bs;
    float* oWx = side ? fWxB : fWxA;
    float* obx = side ? fbxB : fbxA;
    float* oWs = side ? fWsB : fWsA;
    float* obs_ = side ? fbsB : fbsA;

    __shared__ float rv[EMBED];
    if (tid < EMBED) rv[tid] = (r < EMBED) ? W2[r * EMBED + tid] : b2[tid];
    __syncthreads();

    if (tid < EL) {
        float acc = 0.f;
        for (int t = 0; t < EMBED; ++t) acc += rv[t] * Wx[t * EL + tid];
        if (r < EMBED) oWx[r * EL + tid] = acc;
        else           obx[tid] = acc + bx[tid];
    } else if (tid < EL + NQ) {
        const int q = tid - EL;
        float acc = 0.f;
        for (int t = 0; t < EMBED; ++t) acc += rv[t] * Ws[t * NQ + q];
        if (r < EMBED) oWs[r * NQ + q] = acc;
        else           obs_[q] = acc + bs[q];
    }
}

// ---------------------------------------------------------------------------
// Kernel A: 4 source agents, 512 threads, 3 barriers:
//  P1 msg gather (obs_edge read per-thread, L1 broadcast)  | sync
//  P2 segsum S                                             | sync
//  P3 wide-GEMV pass1 + {pass2 e-units || logit partials}  | sync
//  P4 elems write + pxy_base + logit-combine/argmax
// ---------------------------------------------------------------------------
__global__ __launch_bounds__(NTHR, 8) void enc512_kernel(
    const float* __restrict__ obj_x, const float* __restrict__ obj_pos,
    const float* __restrict__ agent_pos,
    const float* __restrict__ enc_W1, const float* __restrict__ enc_b1,
    const float* __restrict__ fWxA, const float* __restrict__ fbxA,
    const float* __restrict__ fWsA, const float* __restrict__ fbsA,
    const int* __restrict__ obs_edge,
    float* __restrict__ elems_base, int* __restrict__ npred_out,
    float2* __restrict__ pxy_base)
{
    const int blk = blockIdx.x, tid = threadIdx.x;
    const int i0  = blk * G;
    const int col = tid & 127, q = tid >> 7;

    __shared__ float  msg[G * OBSD][20];
    __shared__ float4 SG[EMBED];          // segsum, [c] -> 4 agents
    __shared__ float  Lp[2][G * NQ];      // logit split-K2 partials
    __shared__ float4 Pp[2][EL];          // elems split-K2 partials

    // P1: msg gather, obs index read directly (18 threads share one o -> L1)
    for (int idx = tid; idx < G * OBSD * ORIG; idx += NTHR) {
        const int r = idx / ORIG, c = idx % ORIG;
        const int g = r >> 3, d = r & 7;
        const int o = obs_edge[A_N * OBSD + (i0 + g) * OBSD + d];
        float v;
        if (c < 16) v = obj_x[o * 16 + c];
        else        v = obj_pos[o * 2 + (c - 16)] - agent_pos[(i0 + g) * 2 + (c - 16)];
        msg[r][c] = v;
    }
    __syncthreads();

    // P2: S = segsum relu(msg@W1+b1); thread (col,q) -> agent q
    {
        float w1[ORIG];
#pragma unroll
        for (int c = 0; c < ORIG; ++c) w1[c] = enc_W1[c * EMBED + col];
        const float b1 = enc_b1[col];
        float acc = 0.f;
#pragma unroll
        for (int d = 0; d < OBSD; ++d) {
            const int r = q * OBSD + d;
            const float4* mr = (const float4*)&msg[r][0];
            const float4 m0 = mr[0], m1 = mr[1], m2 = mr[2], m3 = mr[3];
            const float2 m4 = *(const float2*)&msg[r][16];
            float h = b1
                + m0.x*w1[0]  + m0.y*w1[1]  + m0.z*w1[2]  + m0.w*w1[3]
                + m1.x*w1[4]  + m1.y*w1[5]  + m1.z*w1[6]  + m1.w*w1[7]
                + m2.x*w1[8]  + m2.y*w1[9]  + m2.z*w1[10] + m2.w*w1[11]
                + m3.x*w1[12] + m3.y*w1[13] + m3.z*w1[14] + m3.w*w1[15]
                + m4.x*w1[16] + m4.y*w1[17];
            acc += fmaxf(h, 0.f);
        }
        ((float*)&SG[col])[q] = acc;
    }
    __syncthreads();

    // P3: elems partials (pass1: units 0-511; pass2: units 512-575 on tid<64)
    //     || logit split-K2 partials on tid 64..199 during pass2
    {
        // pass 1
        {
            const int u = tid;
            const int h = (u >= EL) ? 1 : 0;
            const int e = u - h * EL;
            float4 acc = {0.f, 0.f, 0.f, 0.f};
            const int c0 = 64 * h;
#pragma unroll 8
            for (int c = c0; c < c0 + 64; ++c) {
                const float4 s = SG[c];
                const float  w = fWxA[c * EL + e];
                acc.x += s.x * w; acc.y += s.y * w; acc.z += s.z * w; acc.w += s.w * w;
            }
            Pp[h][e] = acc;
        }
        // pass 2: e-units 512..575 (tid<64) || logit units (tid 64..199)
        if (tid < 64) {
            const int e = (NTHR + tid) - EL;          // 224..287, h = 1
            float4 acc = {0.f, 0.f, 0.f, 0.f};
#pragma unroll 8
            for (int c = 64; c < 128; ++c) {
                const float4 s = SG[c];
                const float  w = fWxA[c * EL + e];
                acc.x += s.x * w; acc.y += s.y * w; acc.z += s.z * w; acc.w += s.w * w;
            }
            Pp[1][e] = acc;
        } else if (tid < 64 + 2 * G * NQ) {
            const int lu = tid - 64, pp = lu / (G * NQ), lq = lu % (G * NQ);
            const int g = lq / NQ, qq = lq % NQ;
            float v = 0.f;
            const int c0 = 64 * pp;
#pragma unroll 8
            for (int c = c0; c < c0 + 64; ++c)
                v += ((const float*)&SG[c])[g] * fWsA[c * NQ + qq];
            Lp[pp][lq] = v;
        }
    }
    __syncthreads();

    // P4: elems write || pxy_base || logit combine+argmax
    if (tid < EL) {
        const float4 a = Pp[0][tid], b = Pp[1][tid];
        const float bx = fbxA[tid];
        elems_base[(size_t)(i0 + 0) * EL + tid] = a.x + b.x + bx;
        elems_base[(size_t)(i0 + 1) * EL + tid] = a.y + b.y + bx;
        elems_base[(size_t)(i0 + 2) * EL + tid] = a.z + b.z + bx;
        elems_base[(size_t)(i0 + 3) * EL + tid] = a.w + b.w + bx;
    } else if (tid < EL + G * MAXO) {
        const int u = tid - EL;
        const int g = u >> 4, m = u & 15;
        const int e16 = m * ORIG + 16, e17 = e16 + 1;
        const float px = ((const float*)&Pp[0][e16])[g] + ((const float*)&Pp[1][e16])[g]
                       + fbxA[e16];
        const float py = ((const float*)&Pp[0][e17])[g] + ((const float*)&Pp[1][e17])[g]
                       + fbxA[e17];
        pxy_base[(size_t)(i0 + g) * MAXO + m] = make_float2(px, py);
    } else if (tid >= 448 && tid < 448 + G) {
        const int g = tid - 448;
        int best = 0; float bv = -3.0e38f;
        for (int qq = 0; qq < NQ; ++qq) {
            const float v = Lp[0][g * NQ + qq] + Lp[1][g * NQ + qq] + fbsA[qq];
            if (v > bv) { bv = v; best = qq; }
        }
        npred_out[i0 + g] = best;
    }
}

// ---------------------------------------------------------------------------
// Kernel B: 4 target agents, 512 threads, 8 barriers; wave-pair per agent
// for compaction/dedup (metadata computed per-thread from comm_edge/npred).
// ---------------------------------------------------------------------------
__global__ __launch_bounds__(NTHR, 8) void merge512_kernel(
    const float* __restrict__ agent_pos,
    const float* __restrict__ menc_W1, const float* __restrict__ menc_b1,
    const float* __restrict__ fWxB, const float* __restrict__ fbxB,
    const float* __restrict__ fWsB, const float* __restrict__ fbsB,
    const int* __restrict__ comm_edge,
    const float* __restrict__ elems_base, const int* __restrict__ npred,
    const float2* __restrict__ pxy_base,
    float* __restrict__ out_dec, float* __restrict__ out_batch,
    float* __restrict__ out_mask)
{
    const int blk = blockIdx.x, tid = threadIdx.x;
    const int i0  = blk * G;
    const int col = tid & 127, q = tid >> 7;
    const int lane = tid & 63, wv = tid >> 6;
    const int w = wv >> 1, half = wv & 1;

    __shared__ float2 pxy[G][KCAND];
    __shared__ __align__(8)  int    vl[G][KCAND + 2];  // compacted idx + sentinels
    __shared__ __align__(16) float2 pv[G][KCAND];      // compacted positions
    __shared__ int    wcv[G][2], kcv[G][2];
    __shared__ int    nv[G], kcnt[G];
    __shared__ int    klist[G][MAXO];
    __shared__ float  kc[G][MAXO][20];
    __shared__ float4 Hs[EMBED];
    __shared__ float  Lp[2][G * NQ];
    __shared__ int    n2s[G];
    __shared__ float4 Pp[2][EL];

    // P1: per-thread metadata (16 threads share each edge -> L1) + position
    const int k = 64 * half + lane;
    const int kd = k >> 4, km = k & 15;
    const int e_edge = (i0 + w) * DEG + kd;
    const int jsrc = comm_edge[e_edge];
    const int itgt = comm_edge[A_N * DEG + e_edge];
    float2 p = pxy_base[(size_t)jsrc * MAXO + km];
    p.x += agent_pos[jsrc * 2 + 0] - agent_pos[itgt * 2 + 0];
    p.y += agent_pos[jsrc * 2 + 1] - agent_pos[itgt * 2 + 1];
    const int val = (km < npred[jsrc]) ? 1 : 0;
    pxy[w][k] = p;
    {
        const unsigned long long bal = __ballot(val);
        const int pref = (int)__popcll(bal << (63 - lane));
        if (lane == 63) wcv[w][half] = (int)__popcll(bal);
        __syncthreads();
        // P2: compacted write
        const int base = half ? wcv[w][0] : 0;
        if (val) { vl[w][base + pref - 1] = k; pv[w][base + pref - 1] = p; }
        if (lane == 0 && half == 0) {
            const int tot = wcv[w][0] + wcv[w][1];
            nv[w] = tot;
            vl[w][tot] = 0x7fffffff;         // sentinels for 2-wide scan
            vl[w][tot + 1] = 0x7fffffff;
        }
        __syncthreads();
    }

    // P3: dedup scan (2-wide) + ballot
    {
        const int nvg = nv[w];
        int dup = 0;
        for (int idx = 0; idx < nvg; idx += 2) {
            const int2   kk = *(const int2*)&vl[w][idx];
            const float4 pq = *(const float4*)&pv[w][idx];
            if (kk.x >= k) break;
            float dx = pq.x - p.x, dy = pq.y - p.y;
            dup |= (dx * dx + dy * dy < THRES2) ? 1 : 0;
            if (kk.y >= k) break;
            dx = pq.z - p.x; dy = pq.w - p.y;
            dup |= (dx * dx + dy * dy < THRES2) ? 1 : 0;
        }
        const int kp = (val && !dup) ? 1 : 0;
        const unsigned long long bal = __ballot(kp);
        const int pref = (int)__popcll(bal << (63 - lane));
        if (lane == 63) kcv[w][half] = (int)__popcll(bal);
        __syncthreads();
        // P4: klist write + cap
        const int cnt = (half ? kcv[w][0] : 0) + pref;
        if (kp && cnt <= MAXO - 1) klist[w][cnt - 1] = k;
        if (lane == 0 && half == 0) {
            const int tot = kcv[w][0] + kcv[w][1];
            kcnt[w] = (tot < MAXO - 1) ? tot : (MAXO - 1);
        }
        __syncthreads();
    }

    // P5: gather kept rows (j recomputed from comm_edge -> L1)
    for (int idx = tid; idx < G * EL; idx += NTHR) {
        const int g = idx / EL, rem = idx % EL;
        const int s = rem / ORIG, c = rem % ORIG;
        if (s < kcnt[g]) {
            const int kk = klist[g][s], d = kk >> 4, m = kk & 15;
            const int j = comm_edge[(i0 + g) * DEG + d];
            float v;
            if (c < 16) v = elems_base[(size_t)j * EL + m * ORIG + c];
            else        v = (c == 16) ? pxy[g][kk].x : pxy[g][kk].y;
            kc[g][s][c] = v;
        }
    }
    __syncthreads();

    // P6: hsum: thread (col,q) -> agent q over <=15 kept rows
    {
        float w1[ORIG];
#pragma unroll
        for (int c = 0; c < ORIG; ++c) w1[c] = menc_W1[c * EMBED + col];
        const float b1 = menc_b1[col];
        const int nk = kcnt[q];
        float hs = 0.f;
        for (int s = 0; s < nk; ++s) {
            const float4* mr = (const float4*)&kc[q][s][0];
            const float4 m0 = mr[0], m1 = mr[1], m2 = mr[2], m3 = mr[3];
            const float2 m4 = *(const float2*)&kc[q][s][16];
            float h = b1
                + m0.x*w1[0]  + m0.y*w1[1]  + m0.z*w1[2]  + m0.w*w1[3]
                + m1.x*w1[4]  + m1.y*w1[5]  + m1.z*w1[6]  + m1.w*w1[7]
                + m2.x*w1[8]  + m2.y*w1[9]  + m2.z*w1[10] + m2.w*w1[11]
                + m3.x*w1[12] + m3.y*w1[13] + m3.z*w1[14] + m3.w*w1[15]
                + m4.x*w1[16] + m4.y*w1[17];
            hs += fmaxf(h, 0.f);
        }
        ((float*)&Hs[col])[q] = hs;
    }
    __syncthreads();

    // P7: decode partials (pass1 + pass2 e-units on tid<64) || logit partials
    {
        {
            const int u = tid;
            const int h = (u >= EL) ? 1 : 0;
            const int e = u - h * EL;
            float4 acc = {0.f, 0.f, 0.f, 0.f};
            const int c0 = 64 * h;
#pragma unroll 8
            for (int c = c0; c < c0 + 64; ++c) {
                const float4 s = Hs[c];
                const float  ww = fWxB[c * EL + e];
                acc.x += s.x * ww; acc.y += s.y * ww; acc.z += s.z * ww; acc.w += s.w * ww;
            }
            Pp[h][e] = acc;
        }
        if (tid < 64) {
            const int e = (NTHR + tid) - EL;          // 224..287, h = 1
            float4 acc = {0.f, 0.f, 0.f, 0.f};
#pragma unroll 8
            for (int c = 64; c < 128; ++c) {
                const float4 s = Hs[c];
                const float  ww = fWxB[c * EL + e];
                acc.x += s.x * ww; acc.y += s.y * ww; acc.z += s.z * ww; acc.w += s.w * ww;
            }
            Pp[1][e] = acc;
        } else if (tid < 64 + 2 * G * NQ) {
            const int lu = tid - 64, pp = lu / (G * NQ), lq = lu % (G * NQ);
            const int g = lq / NQ, qq = lq % NQ;
            float v = 0.f;
            const int c0 = 64 * pp;
#pragma unroll 8
            for (int c = c0; c < c0 + 64; ++c)
                v += ((const float*)&Hs[c])[g] * fWsB[c * NQ + qq];
            Lp[pp][lq] = v;
        }
    }
    __syncthreads();

    // P8: dreg combine (registers) || logit combine + argmax -> n2s
    float4 dreg = {0.f, 0.f, 0.f, 0.f};
    if (tid < EL) {
        const float4 a = Pp[0][tid], b = Pp[1][tid];
        const float bx = fbxB[tid];
        dreg.x = a.x + b.x + bx; dreg.y = a.y + b.y + bx;
        dreg.z = a.z + b.z + bx; dreg.w = a.w + b.w + bx;
    } else if (tid >= 448 && tid < 448 + G) {
        const int g = tid - 448;
        int best = 0; float bv = -3.0e38f;
        for (int qq = 0; qq < NQ; ++qq) {
            const float v = Lp[0][g * NQ + qq] + Lp[1][g * NQ + qq] + fbsB[qq];
            if (v > bv) { bv = v; best = qq; }
        }
        n2s[g] = best;
    }
    __syncthreads();

    // P9: masked write + batch/mask
    if (tid < EL) {
        const int m = tid / ORIG;
        out_dec[(size_t)(i0 + 0) * EL + tid] = (m < n2s[0]) ? dreg.x : 0.f;
        out_dec[(size_t)(i0 + 1) * EL + tid] = (m < n2s[1]) ? dreg.y : 0.f;
        out_dec[(size_t)(i0 + 2) * EL + tid] = (m < n2s[2]) ? dreg.z : 0.f;
        out_dec[(size_t)(i0 + 3) * EL + tid] = (m < n2s[3]) ? dreg.w : 0.f;
    } else if (tid >= NTHR - G * MAXO) {
        const int idx = tid - (NTHR - G * MAXO);
        const int g = idx >> 4, m = idx & 15;
        out_batch[(i0 + g) * MAXO + m] = (float)(i0 + g);
        out_mask[(i0 + g) * MAXO + m]  = (m < n2s[g]) ? 1.f : 0.f;
    }
}

extern "C" void kernel_launch(void* const* d_in, const int* in_sizes, int n_in,
                              void* d_out, int out_size, void* d_ws, size_t ws_size,
                              hipStream_t stream)
{
    const float* obj_x     = (const float*)d_in[0];
    const float* obj_pos   = (const float*)d_in[1];
    const float* agent_pos = (const float*)d_in[2];
    const float* enc_W1    = (const float*)d_in[3];
    const float* enc_b1    = (const float*)d_in[4];
    const float* enc_W2    = (const float*)d_in[5];
    const float* enc_b2    = (const float*)d_in[6];
    const float* mdec_Ws   = (const float*)d_in[7];
    const float* mdec_bs   = (const float*)d_in[8];
    const float* mdec_Wx   = (const float*)d_in[9];
    const float* mdec_bx   = (const float*)d_in[10];
    const float* menc_W1   = (const float*)d_in[11];
    const float* menc_b1   = (const float*)d_in[12];
    const float* menc_W2   = (const float*)d_in[13];
    const float* menc_b2   = (const float*)d_in[14];
    const float* dec_Ws    = (const float*)d_in[15];
    const float* dec_bs    = (const float*)d_in[16];
    const float* dec_Wx    = (const float*)d_in[17];
    const float* dec_bx    = (const float*)d_in[18];
    const int*   obs_edge  = (const int*)d_in[19];
    const int*   comm_edge = (const int*)d_in[20];

    char* ws = (char*)d_ws;
    size_t off = 0;
    float*  elems_base = (float*)(ws + off);  off += (size_t)A_N * EL * sizeof(float);
    int*    npred      = (int*)(ws + off);    off += (size_t)A_N * sizeof(int);
    float2* pxy_base   = (float2*)(ws + off); off += (size_t)A_N * MAXO * sizeof(float2);
    float*  fWxA = (float*)(ws + off);        off += (size_t)EMBED * EL * sizeof(float);
    float*  fbxA = (float*)(ws + off);        off += (size_t)EL * sizeof(float);
    float*  fWsA = (float*)(ws + off);        off += (size_t)EMBED * NQ * sizeof(float);
    float*  fbsA = (float*)(ws + off);        off += 32 * sizeof(float);
    float*  fWxB = (float*)(ws + off);        off += (size_t)EMBED * EL * sizeof(float);
    float*  fbxB = (float*)(ws + off);        off += (size_t)EL * sizeof(float);
    float*  fWsB = (float*)(ws + off);        off += (size_t)EMBED * NQ * sizeof(float);
    float*  fbsB = (float*)(ws + off);        off += 32 * sizeof(float);

    float* out_dec   = (float*)d_out;
    float* out_batch = out_dec + (size_t)A_N * EL;
    float* out_mask  = out_batch + (size_t)A_N * MAXO;

    prep_kernel<<<258, 320, 0, stream>>>(
        enc_W2, enc_b2, mdec_Wx, mdec_Ws, mdec_bx, mdec_bs,
        menc_W2, menc_b2, dec_Wx, dec_Ws, dec_bx, dec_bs,
        fWxA, fbxA, fWsA, fbsA, fWxB, fbxB, fWsB, fbsB);

    enc512_kernel<<<NBLK, NTHR, 0, stream>>>(
        obj_x, obj_pos, agent_pos, enc_W1, enc_b1,
        fWxA, fbxA, fWsA, fbsA, obs_edge,
        elems_base, npred, pxy_base);

    merge512_kernel<<<NBLK, NTHR, 0, stream>>>(
        agent_pos, menc_W1, menc_b1,
        fWxB, fbxB, fWsB, fbsB, comm_edge,
        elems_base, npred, pxy_base, out_dec, out_batch, out_mask);
}